// Round 1
// baseline (266.436 us; speedup 1.0000x reference)
//
#include <hip/hip_runtime.h>

typedef __bf16 bf16x8 __attribute__((ext_vector_type(8)));
typedef float f32x4 __attribute__((ext_vector_type(4)));

#define TID ((int)threadIdx.x)

constexpr int Nn = 64, Cc = 64, Tt = 300, Vv = 25;
constexpr int Fin = 1600;          // V*C = V*CO
constexpr int RowsT = 19200;       // N*T
constexpr int TBR = 16;            // t-rows per block
constexpr int NTB = 19;            // ceil(300/16)
constexpr int RAWE = Cc * TBR * Vv; // 25600 bf16 elements
constexpr int YPAD = 20;           // padded y row (16 + 4) -> 40B rows, 8B-aligned b64 writes
constexpr float EPSv = 1e-5f;

__device__ __forceinline__ unsigned short f2b(float f) {
  unsigned u = __float_as_uint(f);
  return (unsigned short)((u + 0x7fffu + ((u >> 16) & 1u)) >> 16); // RNE
}
__device__ __forceinline__ float b2f(unsigned short h) {
  return __uint_as_float(((unsigned)h) << 16);
}
__device__ __forceinline__ unsigned long long pack4(float a, float b, float c, float d) {
  return (unsigned long long)f2b(a)
       | ((unsigned long long)f2b(b) << 16)
       | ((unsigned long long)f2b(c) << 32)
       | ((unsigned long long)f2b(d) << 48);
}

// Stage x-tile (bf16, layout [c][t][v] flat), lin_w -> swizzled bT, combo = (gather off | mask)
__device__ __forceinline__ void stage_all(
    const float* __restrict__ x, const float* __restrict__ lin_w,
    const float* __restrict__ feat_mask, const int* __restrict__ shift_in,
    int n, int t0, int validg,
    unsigned short* raw, unsigned short* bT, unsigned* combo)
{
  const int base = n * 480000 + t0 * 25;  // x flat index of (n, c=0, t0, v=0)
  if (validg == TBR * 25) {
    #pragma unroll
    for (int i = 0; i < 25; ++i) {
      int q = TID + i * 256;              // 0..6399 float4 groups
      int c = q / 100;
      int g4 = (q - c * 100) * 4;         // 0..396, 16B aligned (proven: all terms %4==0)
      float4 xv = *reinterpret_cast<const float4*>(x + base + c * 7500 + g4);
      *reinterpret_cast<unsigned long long*>(raw + q * 4) = pack4(xv.x, xv.y, xv.z, xv.w);
    }
  } else {
    #pragma unroll
    for (int i = 0; i < 25; ++i) {
      int q = TID + i * 256;
      int c = q / 100;
      int g4 = (q - c * 100) * 4;
      float4 xv = make_float4(0.f, 0.f, 0.f, 0.f);
      if (g4 < validg)                    // validg=300 divisible by 4 -> groups are all-or-nothing
        xv = *reinterpret_cast<const float4*>(x + base + c * 7500 + g4);
      *reinterpret_cast<unsigned long long*>(raw + q * 4) = pack4(xv.x, xv.y, xv.z, xv.w);
    }
  }
  // lin_w (C,CO) -> bT[d][c] bf16 with XOR swizzle on 8-elem (16B) blocks
  #pragma unroll
  for (int i = 0; i < 16; ++i) {
    int e = TID + i * 256;                // 0..4095
    int c = e >> 6, d = e & 63;
    bT[d * 64 + (((c >> 3) ^ (d & 7)) * 8) + (c & 7)] = f2b(lin_w[e]);
  }
  // combo[j]: high16 = raw-LDS element offset of gather source, low16 = bf16(tanh(fm)+1)
  for (int j = TID; j < Fin; j += 256) {
    int s = shift_in[j];                          // source column v2*64 + c2
    unsigned off = (unsigned)((s & 63) * 400 + (s >> 6));  // c2*400 + v2
    float m = tanhf(feat_mask[j]) + 1.0f;
    combo[j] = (off << 16) | (unsigned)f2b(m);
  }
}

// B fragments for mfma_f32_16x16x32_bf16: B[k][col], col=lane&15, k=(lane>>4)*8+i
__device__ __forceinline__ void load_bfr(const unsigned short* bT, bf16x8 bf[2][4]) {
  int l = TID & 63;
  int row = l & 15, grp = l >> 4;
  #pragma unroll
  for (int ks = 0; ks < 2; ++ks)
    #pragma unroll
    for (int nt = 0; nt < 4; ++nt) {
      int d = nt * 16 + row;
      int blk = (ks * 4 + grp) ^ (d & 7);
      bf[ks][nt] = *reinterpret_cast<const bf16x8*>(bT + d * 64 + blk * 8);
    }
}

// A fragment: A[t][k=c] for joint v; row=lane&15, k=(lane>>4)*8+i; gather+mask on the fly
__device__ __forceinline__ bf16x8 build_a(const unsigned short* raw, const unsigned* combo,
                                          int v, int ks) {
  int l = TID & 63;
  int t = l & 15, grp = l >> 4;
  int jb = v * 64 + ks * 32 + grp * 8;
  bf16x8 a;
  #pragma unroll
  for (int i = 0; i < 8; ++i) {
    unsigned cb = combo[jb + i];
    float m = __uint_as_float((cb & 0xffffu) << 16);
    float xv = b2f(raw[(cb >> 16) + t * 25]);
    a[i] = (__bf16)(xv * m);
  }
  return a;
}

__global__ __launch_bounds__(256, 2) void k_stats(
    const float* __restrict__ x, const float* __restrict__ lin_w,
    const float* __restrict__ feat_mask, const int* __restrict__ shift_in,
    float* __restrict__ wsum)  // [0:1600) = sum, [1600:3200) = sumsq
{
  __shared__ __align__(16) unsigned short raw[RAWE];
  __shared__ __align__(16) unsigned short bT[Cc * 64];
  __shared__ __align__(16) unsigned combo[Fin];

  int bid = blockIdx.x;
  int n = bid / NTB, tb = bid - n * NTB;
  int t0 = tb * TBR;
  int valid = min(TBR, Tt - t0);
  stage_all(x, lin_w, feat_mask, shift_in, n, t0, valid * 25, raw, bT, combo);
  __syncthreads();

  bf16x8 bf[2][4];
  load_bfr(bT, bf);
  int w = TID >> 6, l = TID & 63;
  float* wsq = wsum + Fin;
  for (int v = w; v < Vv; v += 4) {
    bf16x8 a0 = build_a(raw, combo, v, 0);
    bf16x8 a1 = build_a(raw, combo, v, 1);
    #pragma unroll
    for (int nt = 0; nt < 4; ++nt) {
      f32x4 acc = {0.f, 0.f, 0.f, 0.f};
      acc = __builtin_amdgcn_mfma_f32_16x16x32_bf16(a0, bf[0][nt], acc, 0, 0, 0);
      acc = __builtin_amdgcn_mfma_f32_16x16x32_bf16(a1, bf[1][nt], acc, 0, 0, 0);
      // padded rows are zero -> contribute 0 to both sums
      float p = acc[0] + acc[1] + acc[2] + acc[3];
      float q = acc[0]*acc[0] + acc[1]*acc[1] + acc[2]*acc[2] + acc[3]*acc[3];
      p += __shfl_xor(p, 16); p += __shfl_xor(p, 32);
      q += __shfl_xor(q, 16); q += __shfl_xor(q, 32);
      if ((l & 48) == 0) {
        int col = v * 64 + nt * 16 + (l & 15);
        atomicAdd(&wsum[col], p);
        atomicAdd(&wsq[col], q);
      }
    }
  }
}

__global__ __launch_bounds__(256, 1) void k_main(
    const float* __restrict__ x, const float* __restrict__ lin_w,
    const float* __restrict__ feat_mask, const int* __restrict__ shift_in,
    const int* __restrict__ shift_out, const float* __restrict__ gamma,
    const float* __restrict__ beta, const float* __restrict__ wsum,
    float* __restrict__ out)
{
  __shared__ __align__(16) unsigned short raw[RAWE];
  __shared__ __align__(16) unsigned short bT[Cc * 64];
  __shared__ __align__(16) unsigned combo[Fin];
  __shared__ __align__(16) unsigned short ylds[Fin * YPAD];  // y staged bf16, [col][t+pad]
  __shared__ __align__(16) float4 epi[Fin];  // {scale, off, yrow_elem_off_bits, 0}

  int bid = blockIdx.x;
  int n = bid / NTB, tb = bid - n * NTB;
  int t0 = tb * TBR;
  int valid = min(TBR, Tt - t0);
  int validg = valid * 25;
  stage_all(x, lin_w, feat_mask, shift_in, n, t0, validg, raw, bT, combo);

  // batch stats -> temp arrays living in (currently unused) ylds region
  float* tmean = reinterpret_cast<float*>(ylds);
  float* trstd = tmean + Fin;
  for (int s = TID; s < Fin; s += 256) {
    float sm = wsum[s] * (1.0f / RowsT);
    float sq = wsum[Fin + s] * (1.0f / RowsT);
    float var = fmaxf(sq - sm * sm, 0.f);
    tmean[s] = sm;
    trstd[s] = rsqrtf(var + EPSv);
  }
  __syncthreads();

  // per-output-column BN fold: bias cancels ((y+b) - (mean+b)) -> ignore lin_b
  for (int k = TID; k < Fin; k += 256) {
    int s2 = shift_out[k];
    float sc = gamma[k] * trstd[s2];
    float of = beta[k] - tmean[s2] * sc;
    epi[k] = make_float4(sc, of, __uint_as_float((unsigned)(s2 * YPAD)), 0.f);
  }
  bf16x8 bf[2][4];
  load_bfr(bT, bf);
  __syncthreads();  // epi built; ylds temp region now free

  int w = TID >> 6, l = TID & 63, grp = l >> 4;
  for (int v = w; v < Vv; v += 4) {
    bf16x8 a0 = build_a(raw, combo, v, 0);
    bf16x8 a1 = build_a(raw, combo, v, 1);
    #pragma unroll
    for (int nt = 0; nt < 4; ++nt) {
      f32x4 acc = {0.f, 0.f, 0.f, 0.f};
      acc = __builtin_amdgcn_mfma_f32_16x16x32_bf16(a0, bf[0][nt], acc, 0, 0, 0);
      acc = __builtin_amdgcn_mfma_f32_16x16x32_bf16(a1, bf[1][nt], acc, 0, 0, 0);
      int col = v * 64 + nt * 16 + (l & 15);
      // rows grp*4 + 0..3 packed into one b64 write
      *reinterpret_cast<unsigned long long*>(ylds + col * YPAD + grp * 4) =
          pack4(acc[0], acc[1], acc[2], acc[3]);
    }
  }
  __syncthreads();

  // epilogue: BN + residual + relu, coalesced fp32 stores
  const int obase = n * 480000 + t0 * 25;
  for (int it = 0; it < 100; ++it) {
    int idx = it * 256 + TID;     // 0..25599
    int d = idx / 400;
    int f = idx - d * 400;        // t_local*25 + v
    if (f < validg) {
      int t = f / 25;
      int v = f - t * 25;
      float4 e = epi[v * 64 + d];
      float yv = b2f(ylds[__float_as_uint(e.z) + t]);
      float xr = b2f(raw[d * 400 + f]);   // residual x[n,d,t,v]
      float o = fmaf(yv, e.x, e.y) + xr;
      out[obase + d * 7500 + f] = fmaxf(o, 0.f);
    }
  }
}

extern "C" void kernel_launch(void* const* d_in, const int* in_sizes, int n_in,
                              void* d_out, int out_size, void* d_ws, size_t ws_size,
                              hipStream_t stream) {
  (void)in_sizes; (void)n_in; (void)out_size; (void)ws_size;
  const float* x        = (const float*)d_in[0];
  const float* lin_w    = (const float*)d_in[1];
  // d_in[2] = lin_b: provably cancels in BatchNorm -> unused
  const float* feat_mask= (const float*)d_in[3];
  const float* gamma    = (const float*)d_in[4];
  const float* beta     = (const float*)d_in[5];
  const int*   shift_in = (const int*)d_in[6];
  const int*   shift_out= (const int*)d_in[7];
  float* wsum = (float*)d_ws;

  hipMemsetAsync(d_ws, 0, 2 * Fin * sizeof(float), stream);
  k_stats<<<Nn * NTB, 256, 0, stream>>>(x, lin_w, feat_mask, shift_in, wsum);
  k_main <<<Nn * NTB, 256, 0, stream>>>(x, lin_w, feat_mask, shift_in, shift_out,
                                        gamma, beta, wsum, (float*)d_out);
}

// Round 2
// 135.734 us; speedup vs baseline: 1.9629x; 1.9629x over previous
//
#include <hip/hip_runtime.h>

typedef __bf16 bf16x8 __attribute__((ext_vector_type(8)));
typedef float f32x4 __attribute__((ext_vector_type(4)));

#define TID ((int)threadIdx.x)

constexpr int Nn = 64, Cc = 64, Tt = 300, Vv = 25;
constexpr int Fin = 1600;          // V*C = V*CO
constexpr int RowsT = 19200;       // N*T
constexpr int TBR = 16;            // t-rows per block
constexpr int NTB = 19;            // ceil(300/16)
constexpr int RAWE = Cc * TBR * Vv; // 25600 bf16 elements (51200 B)
constexpr int YP = 21;             // ylds row stride (odd -> coprime with banks)
constexpr float EPSv = 1e-5f;

__device__ __forceinline__ unsigned short f2b(float f) {
  unsigned u = __float_as_uint(f);
  return (unsigned short)((u + 0x7fffu + ((u >> 16) & 1u)) >> 16); // RNE
}
__device__ __forceinline__ float b2f(unsigned short h) {
  return __uint_as_float(((unsigned)h) << 16);
}
__device__ __forceinline__ unsigned long long pack4(float a, float b, float c, float d) {
  return (unsigned long long)f2b(a)
       | ((unsigned long long)f2b(b) << 16)
       | ((unsigned long long)f2b(c) << 32)
       | ((unsigned long long)f2b(d) << 48);
}

// ---- staging (512 threads) ----
__device__ __forceinline__ void stage_raw(const float* __restrict__ x,
                                          int n, int t0, int validg,
                                          unsigned short* raw) {
  const int base = n * 480000 + t0 * 25;  // x flat index of (n, c=0, t0, v=0)
  if (validg == TBR * 25) {
    #pragma unroll
    for (int i = 0; i < 13; ++i) {
      int q = TID + i * 512;              // float4 group id
      if (q < 6400) {
        int c = q / 100;
        int g4 = (q - c * 100) * 4;       // 16B aligned
        float4 xv = *reinterpret_cast<const float4*>(x + base + c * 7500 + g4);
        *reinterpret_cast<unsigned long long*>(raw + q * 4) = pack4(xv.x, xv.y, xv.z, xv.w);
      }
    }
  } else {
    #pragma unroll
    for (int i = 0; i < 13; ++i) {
      int q = TID + i * 512;
      if (q < 6400) {
        int c = q / 100;
        int g4 = (q - c * 100) * 4;
        float4 xv = make_float4(0.f, 0.f, 0.f, 0.f);
        if (g4 < validg)                  // validg==300: groups all-or-nothing
          xv = *reinterpret_cast<const float4*>(x + base + c * 7500 + g4);
        *reinterpret_cast<unsigned long long*>(raw + q * 4) = pack4(xv.x, xv.y, xv.z, xv.w);
      }
    }
  }
}

__device__ __forceinline__ void stage_bt(const float* __restrict__ lin_w,
                                         unsigned short* bT) {
  // lin_w (C,CO) -> bT[d][c] bf16 with XOR swizzle on 8-elem (16B) blocks
  #pragma unroll
  for (int i = 0; i < 8; ++i) {
    int e = TID + i * 512;                // 0..4095
    int c = e >> 6, d = e & 63;
    bT[d * 64 + (((c >> 3) ^ (d & 7)) * 8) + (c & 7)] = f2b(lin_w[e]);
  }
}

__device__ __forceinline__ void stage_combo(const float* __restrict__ feat_mask,
                                            const int* __restrict__ shift_in,
                                            unsigned* combo) {
  #pragma unroll
  for (int i = 0; i < 4; ++i) {
    int j = TID + i * 512;
    if (j < Fin) {
      int s = shift_in[j];                              // source column v2*64 + c2
      unsigned off = (unsigned)((s & 63) * 400 + (s >> 6)); // c2*400 + v2
      float m = tanhf(feat_mask[j]) + 1.0f;
      combo[j] = (off << 16) | (unsigned)f2b(m);
    }
  }
}

// B fragments for mfma_f32_16x16x32_bf16: col=lane&15, k=(lane>>4)*8+i (+32 ks)
__device__ __forceinline__ void load_bfr(const unsigned short* bT, bf16x8 bf[2][4]) {
  int l = TID & 63;
  int row = l & 15, grp = l >> 4;
  #pragma unroll
  for (int ks = 0; ks < 2; ++ks)
    #pragma unroll
    for (int nt = 0; nt < 4; ++nt) {
      int d = nt * 16 + row;
      int blk = (ks * 4 + grp) ^ (d & 7);
      bf[ks][nt] = *reinterpret_cast<const bf16x8*>(bT + d * 64 + blk * 8);
    }
}

// A fragment: A[t][k=c] for joint v; t=lane&15, k=(lane>>4)*8+i; gather+mask on the fly
__device__ __forceinline__ bf16x8 build_a(const unsigned short* raw, const unsigned* combo,
                                          int v, int ks) {
  int l = TID & 63;
  int t = l & 15, grp = l >> 4;
  int jb = v * 64 + ks * 32 + grp * 8;
  bf16x8 a;
  #pragma unroll
  for (int i = 0; i < 8; ++i) {
    unsigned cb = combo[jb + i];
    float m = __uint_as_float((cb & 0xffffu) << 16);
    float xv = b2f(raw[(cb >> 16) + t * 25]);
    a[i] = (__bf16)(xv * m);
  }
  return a;
}

__global__ __launch_bounds__(512, 4) void k_stats(
    const float* __restrict__ x, const float* __restrict__ lin_w,
    const float* __restrict__ feat_mask, const int* __restrict__ shift_in,
    float* __restrict__ wsum)  // [0:1600) = sum, [1600:3200) = sumsq
{
  __shared__ __align__(16) unsigned char smem[65792];
  unsigned short* raw   = reinterpret_cast<unsigned short*>(smem);
  unsigned short* bT    = reinterpret_cast<unsigned short*>(smem + 51200);
  unsigned*       combo = reinterpret_cast<unsigned*>(smem + 59392);

  int bid = blockIdx.x;
  int n = bid / NTB, tb = bid - n * NTB;
  int t0 = tb * TBR;
  int valid = min(TBR, Tt - t0);
  stage_raw(x, n, t0, valid * 25, raw);
  stage_bt(lin_w, bT);
  stage_combo(feat_mask, shift_in, combo);
  __syncthreads();

  bf16x8 bf[2][4];
  load_bfr(bT, bf);
  int w = TID >> 6, l = TID & 63;
  float* wsq = wsum + Fin;
  #pragma unroll
  for (int k = 0; k < 4; ++k) {
    int v = w + 8 * k;
    if (v < Vv) {
      bf16x8 a0 = build_a(raw, combo, v, 0);
      bf16x8 a1 = build_a(raw, combo, v, 1);
      #pragma unroll
      for (int nt = 0; nt < 4; ++nt) {
        f32x4 acc = {0.f, 0.f, 0.f, 0.f};
        acc = __builtin_amdgcn_mfma_f32_16x16x32_bf16(a0, bf[0][nt], acc, 0, 0, 0);
        acc = __builtin_amdgcn_mfma_f32_16x16x32_bf16(a1, bf[1][nt], acc, 0, 0, 0);
        // zero-padded t rows contribute 0 to both sums
        float p = acc[0] + acc[1] + acc[2] + acc[3];
        float q = acc[0]*acc[0] + acc[1]*acc[1] + acc[2]*acc[2] + acc[3]*acc[3];
        p += __shfl_xor(p, 16); p += __shfl_xor(p, 32);
        q += __shfl_xor(q, 16); q += __shfl_xor(q, 32);
        if ((l & 48) == 0) {
          int col = v * 64 + nt * 16 + (l & 15);
          atomicAdd(&wsum[col], p);
          atomicAdd(&wsq[col], q);
        }
      }
    }
  }
}

// BN fold per output column, permuted to index d*25+v; entry = {f32 scale, bf16 off, u16 s2*YP}
__global__ void k_epi(const float* __restrict__ wsum, const float* __restrict__ gamma,
                      const float* __restrict__ beta, const int* __restrict__ shift_out,
                      unsigned long long* __restrict__ epi_g) {
  int k = blockIdx.x * 256 + TID;
  if (k >= Fin) return;
  int s2 = shift_out[k];
  float sm = wsum[s2] * (1.0f / RowsT);
  float sq = wsum[Fin + s2] * (1.0f / RowsT);
  float var = fmaxf(sq - sm * sm, 0.f);
  float rstd = rsqrtf(var + EPSv);
  float sc = gamma[k] * rstd;                 // lin_b provably cancels in BN
  unsigned short offb = f2b(beta[k] - sm * sc);
  int d = k & 63, v = k >> 6;
  unsigned long long e = (unsigned long long)__float_as_uint(sc)
                       | ((unsigned long long)offb << 32)
                       | ((unsigned long long)(unsigned)(s2 * YP) << 48);
  epi_g[d * 25 + v] = e;
}

__global__ __launch_bounds__(512, 4) void k_main(
    const float* __restrict__ x, const float* __restrict__ lin_w,
    const float* __restrict__ feat_mask, const int* __restrict__ shift_in,
    const unsigned long long* __restrict__ epi_g, float* __restrict__ out)
{
  // overlay: [0,51200) raw | [51200,59392) bT | [59392,65792) combo
  //          then ylds bf16[1600*21] = [0,67200) after A-frags are in registers
  // epi:     [67200, 80000)
  __shared__ __align__(16) unsigned char smem[80000];
  unsigned short* raw   = reinterpret_cast<unsigned short*>(smem);
  unsigned short* bT    = reinterpret_cast<unsigned short*>(smem + 51200);
  unsigned*       combo = reinterpret_cast<unsigned*>(smem + 59392);
  unsigned short* ylds  = reinterpret_cast<unsigned short*>(smem);
  unsigned long long* epi = reinterpret_cast<unsigned long long*>(smem + 67200);

  int bid = blockIdx.x;
  int n = bid / NTB, tb = bid - n * NTB;
  int t0 = tb * TBR;
  int valid = min(TBR, Tt - t0);
  int validg = valid * 25;

  stage_raw(x, n, t0, validg, raw);
  stage_bt(lin_w, bT);
  stage_combo(feat_mask, shift_in, combo);
  #pragma unroll
  for (int i = 0; i < 4; ++i) {
    int j = TID + i * 512;
    if (j < Fin) epi[j] = epi_g[j];
  }
  __syncthreads();

  // hoist all fragments to registers (raw/bT/combo die after this)
  bf16x8 bf[2][4];
  load_bfr(bT, bf);
  int w = TID >> 6, l = TID & 63, grp = l >> 4;
  bf16x8 areg[4][2];
  #pragma unroll
  for (int k = 0; k < 4; ++k) {
    int v = w + 8 * k;
    if (v < Vv) {
      areg[k][0] = build_a(raw, combo, v, 0);
      areg[k][1] = build_a(raw, combo, v, 1);
    }
  }
  __syncthreads();  // overlay region now reusable as ylds

  #pragma unroll
  for (int k = 0; k < 4; ++k) {
    int v = w + 8 * k;
    if (v < Vv) {
      #pragma unroll
      for (int nt = 0; nt < 4; ++nt) {
        f32x4 acc = {0.f, 0.f, 0.f, 0.f};
        acc = __builtin_amdgcn_mfma_f32_16x16x32_bf16(areg[k][0], bf[0][nt], acc, 0, 0, 0);
        acc = __builtin_amdgcn_mfma_f32_16x16x32_bf16(areg[k][1], bf[1][nt], acc, 0, 0, 0);
        int col = v * 64 + nt * 16 + (l & 15);
        int o = col * YP + grp * 4;       // rows t = grp*4 + j
        #pragma unroll
        for (int j = 0; j < 4; ++j) ylds[o + j] = f2b(acc[j]);
      }
    }
  }
  __syncthreads();

  // epilogue: BN + residual (x re-read from global, L3-hot) + relu, float4 stores
  const int obase = n * 480000 + t0 * 25;
  #pragma unroll
  for (int it = 0; it < 13; ++it) {
    int g = TID + it * 512;               // float4 group id, 0..6399
    if (g < 6400) {
      int d = g / 100;
      int f0 = (g - d * 100) * 4;         // within-(n,d) offset, 0..396
      if (f0 < validg) {
        const float4 xr = *reinterpret_cast<const float4*>(x + obase + d * 7500 + f0);
        float4 o;
        float* op = &o.x;
        const float* xp = &xr.x;
        #pragma unroll
        for (int e = 0; e < 4; ++e) {
          int f = f0 + e;
          int t = f / 25;
          int v = f - t * 25;
          unsigned long long ep = epi[d * 25 + v];
          float sc = __uint_as_float((unsigned)ep);
          float of = b2f((unsigned short)(ep >> 32));
          int s2o = (int)(ep >> 48);
          float y = b2f(ylds[s2o + t]);
          op[e] = fmaxf(fmaf(y, sc, of) + xp[e], 0.f);
        }
        *reinterpret_cast<float4*>(out + obase + d * 7500 + f0) = o;
      }
    }
  }
}

extern "C" void kernel_launch(void* const* d_in, const int* in_sizes, int n_in,
                              void* d_out, int out_size, void* d_ws, size_t ws_size,
                              hipStream_t stream) {
  (void)in_sizes; (void)n_in; (void)out_size; (void)ws_size;
  const float* x        = (const float*)d_in[0];
  const float* lin_w    = (const float*)d_in[1];
  // d_in[2] = lin_b: provably cancels in BatchNorm -> unused
  const float* feat_mask= (const float*)d_in[3];
  const float* gamma    = (const float*)d_in[4];
  const float* beta     = (const float*)d_in[5];
  const int*   shift_in = (const int*)d_in[6];
  const int*   shift_out= (const int*)d_in[7];
  float* wsum = (float*)d_ws;
  unsigned long long* epi_g = (unsigned long long*)((char*)d_ws + 12800);

  hipMemsetAsync(d_ws, 0, 12800, stream);
  k_stats<<<Nn * NTB, 512, 0, stream>>>(x, lin_w, feat_mask, shift_in, wsum);
  k_epi  <<<7, 256, 0, stream>>>(wsum, gamma, beta, shift_out, epi_g);
  k_main <<<Nn * NTB, 512, 0, stream>>>(x, lin_w, feat_mask, shift_in, epi_g, (float*)d_out);
}